// Round 9
// baseline (230.577 us; speedup 1.0000x reference)
//
#include <hip/hip_runtime.h>
#include <stdint.h>

// Problem constants
#define L_    8192
#define N_    8
#define L2_   2048
#define K_    16

typedef unsigned int uint;
typedef unsigned short ushort;
typedef unsigned long long u64;
typedef __attribute__((ext_vector_type(8))) short bh8;   // 8 bf16 (4 VGPRs)
typedef __attribute__((ext_vector_type(4))) float f32x4; // MFMA C/D

// round-to-nearest-even f32 -> bf16 (monotone)
__device__ __forceinline__ ushort f2b(float f){
  uint u = __float_as_uint(f);
  return (ushort)((u + 0x7FFFu + ((u >> 16) & 1u)) >> 16);
}
// monotone float->uint mapping
__device__ __forceinline__ uint ford(float f){
  uint u = __float_as_uint(f);
  return u ^ ((uint)((int)u >> 31) | 0x80000000u);
}
__device__ __forceinline__ float unford(uint u){
  uint v = (u & 0x80000000u) ? (u ^ 0x80000000u) : ~u;
  return __uint_as_float(v);
}

__device__ __forceinline__ void ld8(float* t, const float* p){
  float4 a = *(const float4*)p; float4 b = *(const float4*)(p + 4);
  t[0]=a.x; t[1]=a.y; t[2]=a.z; t[3]=a.w; t[4]=b.x; t[5]=b.y; t[6]=b.z; t[7]=b.w;
}
__device__ __forceinline__ bh8 pack8(const float* v){
  bh8 r;
  #pragma unroll
  for (int j = 0; j < 8; ++j) r[j] = (short)f2b(v[j]);
  return r;
}

// 4-bit spread for Morton interleave
__device__ __forceinline__ uint sp4(uint v){
  return (v & 1u) | ((v & 2u) << 2) | ((v & 4u) << 4) | ((v & 8u) << 6);
}
__device__ __forceinline__ int cell16(float x){
  int i = (int)floorf((x + 4.f) * 2.f);
  return i < 0 ? 0 : (i > 15 ? 15 : i);
}

// ---------------- K0: prep = weight pack + cF+cellId + keep_coords ----------------
// blocks [0,96): pack w1+w2. blocks [96,352): cF + Morton cellId (coalesced
// stride-24 reads happen exactly once, here). blocks [352,544): keep gather.
__global__ __launch_bounds__(256) void prep_pack_k(const float* __restrict__ coords,
                                                   const int* __restrict__ keep,
                                                   const float* __restrict__ w1,
                                                   const float* __restrict__ w2,
                                                   float4* __restrict__ cF,
                                                   uint* __restrict__ cellId,
                                                   float* __restrict__ out0,
                                                   ushort* __restrict__ pw1,
                                                   ushort* __restrict__ pw2){
  int blk = blockIdx.x;
  int tid = threadIdx.x;
  if (blk < 96){
    int e = blk * 256 + tid;                   // e < 24576
    if (e < 8192) pw1[e] = f2b(w1[e]);
    else          pw2[e - 8192] = f2b(w2[e - 8192]);
  } else if (blk < 352){
    int e = (blk - 96) * 256 + tid;            // e = l*8+n, e < 65536
    int l = e >> 3, n = e & 7;
    const float* cr = coords + (size_t)e * 3;
    float x = cr[0], y = cr[1], z = cr[2];
    float cc;
    {
      #pragma clang fp contract(off)
      cc = x*x + y*y + z*z;                    // identical to reference sum(c*c,-1)
    }
    cF[(n << 13) + l] = make_float4(x, y, z, cc);
    uint mort = (sp4((uint)cell16(x)) << 2) | (sp4((uint)cell16(y)) << 1)
              | sp4((uint)cell16(z));          // 12-bit Morton: compact chunks
    cellId[(n << 13) + l] = mort;
  } else {
    int t = (blk - 352) * 256 + tid;           // t < 49152
    int i = t / 24; int rem = t - i * 24;
    out0[t] = coords[(size_t)keep[i] * 24 + rem];
  }
}

// ---------------- K1: per-n counting sort by Morton cell + chunk AABBs ----------------
// 8 blocks, one per n. All global reads coalesced (fixed n -> consecutive l).
__global__ __launch_bounds__(256) void sort_k(const float4* __restrict__ cF,
                                              const uint* __restrict__ cellId,
                                              float4* __restrict__ sCF,
                                              uint* __restrict__ oIdx,
                                              uint* __restrict__ sPos,
                                              float4* __restrict__ cBB){
  __shared__ uint hist[4096];                  // 16 KB; becomes offsets in-place
  __shared__ uint wsum[4];
  int n = blockIdx.x;
  int tid = threadIdx.x, lane = tid & 63, wv = tid >> 6;
  const uint* cid = cellId + (n << 13);
  const float4* cf = cF + (n << 13);

  for (int i = tid; i < 4096; i += 256) hist[i] = 0;
  __syncthreads();
  for (int t = tid; t < 8192; t += 256)
    atomicAdd(&hist[cid[t]], 1u);              // coalesced read + LDS atomic
  __syncthreads();
  // exclusive scan in place: thread owns cells [16t, 16t+16)
  uint tt = 0;
  #pragma unroll
  for (int j = 0; j < 16; ++j) tt += hist[tid * 16 + j];
  uint sc = tt;
  #pragma unroll
  for (int m = 1; m < 64; m <<= 1){
    uint o = __shfl_up(sc, m, 64);
    if (lane >= m) sc += o;
  }
  if (lane == 63) wsum[wv] = sc;
  __syncthreads();
  uint wbase = 0;
  for (int w = 0; w < wv; ++w) wbase += wsum[w];
  uint run = wbase + sc - tt;
  #pragma unroll
  for (int j = 0; j < 16; ++j){
    uint v = hist[tid * 16 + j];
    hist[tid * 16 + j] = run;
    run += v;
  }
  __syncthreads();
  // scatter (intra-cell order nondeterministic: harmless — selection keys are
  // exact (d2, origIdx), independent of visit order)
  for (int t = tid; t < 8192; t += 256){
    uint pos = atomicAdd(&hist[cid[t]], 1u);
    sCF[(n << 13) + pos] = cf[t];              // coalesced read, scattered write
    oIdx[(n << 13) + pos] = (uint)t;
    sPos[(n << 13) + t]   = pos;
  }
  __syncthreads();                             // drains this block's writes
  // chunk AABBs: 128 chunks x 64 pts; 2 threads/chunk, shuffle-combined
  {
    int ch = tid >> 1, half = tid & 1;
    float4 mn = make_float4(3.4e38f, 3.4e38f, 3.4e38f, 0.f);
    float4 mx = make_float4(-3.4e38f, -3.4e38f, -3.4e38f, 0.f);
    for (int j = half * 32; j < half * 32 + 32; ++j){
      float4 p = sCF[(n << 13) + ch * 64 + j];
      mn.x = fminf(mn.x, p.x); mn.y = fminf(mn.y, p.y); mn.z = fminf(mn.z, p.z);
      mx.x = fmaxf(mx.x, p.x); mx.y = fmaxf(mx.y, p.y); mx.z = fmaxf(mx.z, p.z);
    }
    mn.x = fminf(mn.x, __shfl_xor(mn.x, 1, 64));
    mn.y = fminf(mn.y, __shfl_xor(mn.y, 1, 64));
    mn.z = fminf(mn.z, __shfl_xor(mn.z, 1, 64));
    mx.x = fmaxf(mx.x, __shfl_xor(mx.x, 1, 64));
    mx.y = fmaxf(mx.y, __shfl_xor(mx.y, 1, 64));
    mx.z = fmaxf(mx.z, __shfl_xor(mx.z, 1, 64));
    if (half == 0){
      cBB[(n << 8) + ch * 2]     = mn;
      cBB[(n << 8) + ch * 2 + 1] = mx;
    }
  }
}

// ---------------- K2: MFMA MLP, dim-split 4 ways (R5-identical) ----------------
__global__ __launch_bounds__(256) void mlp_k(const float* __restrict__ feat,
                                             const ushort* __restrict__ pw1,
                                             const float* __restrict__ g1,
                                             const float* __restrict__ b1,
                                             const ushort* __restrict__ pw2,
                                             const float* __restrict__ g2,
                                             const float* __restrict__ b2,
                                             uint* __restrict__ fBw){
  __shared__ ushort hlds[16 * 136];
  __shared__ float pm1[4][16], pv1[4][16], pm2[4][16], pv2[4][16];
  int tid = threadIdx.x;
  int lane = tid & 63;
  int h = __builtin_amdgcn_readfirstlane(tid >> 6);
  int quad = lane >> 4, c = lane & 15;
  int rowg = blockIdx.x * 16;

  bh8 a1[2];
  {
    int rg = rowg + c; int l = rg & 2047, nb = rg >> 11;
    const float* xr = feat + (size_t)((l << 3) + nb) * 64 + quad * 8;
    float t0[8];
    ld8(t0, xr);      a1[0] = pack8(t0);
    ld8(t0, xr + 32); a1[1] = pack8(t0);
  }

  f32x4 acc1[2];
  acc1[0] = (f32x4){0.f,0.f,0.f,0.f}; acc1[1] = (f32x4){0.f,0.f,0.f,0.f};
  #pragma unroll
  for (int s = 0; s < 2; ++s){
    #pragma unroll
    for (int t = 0; t < 2; ++t){
      bh8 wb = *(const bh8*)(pw1 + (size_t)(h * 32 + t * 16 + c) * 64 + s * 32 + quad * 8);
      acc1[t] = __builtin_amdgcn_mfma_f32_16x16x32_bf16(a1[s], wb, acc1[t], 0, 0, 0);
    }
  }

  #pragma unroll
  for (int r = 0; r < 4; ++r){
    float s = acc1[0][r] + acc1[1][r];
    #pragma unroll
    for (int m = 1; m < 16; m <<= 1) s += __shfl_xor(s, m, 16);
    if (c == 0) pm1[h][quad * 4 + r] = s;
  }
  __syncthreads();
  float mean1[4], rstd1[4];
  #pragma unroll
  for (int r = 0; r < 4; ++r){
    int row = quad * 4 + r;
    mean1[r] = (pm1[0][row] + pm1[1][row] + pm1[2][row] + pm1[3][row]) * 0.0078125f;
  }
  #pragma unroll
  for (int r = 0; r < 4; ++r){
    float d0 = acc1[0][r] - mean1[r], d1 = acc1[1][r] - mean1[r];
    float s = d0 * d0 + d1 * d1;
    #pragma unroll
    for (int m = 1; m < 16; m <<= 1) s += __shfl_xor(s, m, 16);
    if (c == 0) pv1[h][quad * 4 + r] = s;
  }
  __syncthreads();
  #pragma unroll
  for (int r = 0; r < 4; ++r){
    int row = quad * 4 + r;
    rstd1[r] = rsqrtf((pv1[0][row] + pv1[1][row] + pv1[2][row] + pv1[3][row]) * 0.0078125f + 1e-5f);
  }
  #pragma unroll
  for (int t = 0; t < 2; ++t){
    int col = h * 32 + t * 16 + c;
    float gv = g1[col], bv = b1[col];
    #pragma unroll
    for (int r = 0; r < 4; ++r){
      float v = (acc1[t][r] - mean1[r]) * rstd1[r] * gv + bv;
      hlds[(quad * 4 + r) * 136 + col] = f2b(v);
    }
  }
  __syncthreads();

  f32x4 acc2[2];
  acc2[0] = (f32x4){0.f,0.f,0.f,0.f}; acc2[1] = (f32x4){0.f,0.f,0.f,0.f};
  #pragma unroll
  for (int s = 0; s < 4; ++s){
    bh8 af = *(const bh8*)(hlds + c * 136 + s * 32 + quad * 8);
    #pragma unroll
    for (int t = 0; t < 2; ++t){
      bh8 wb = *(const bh8*)(pw2 + (size_t)(h * 32 + t * 16 + c) * 128 + s * 32 + quad * 8);
      acc2[t] = __builtin_amdgcn_mfma_f32_16x16x32_bf16(af, wb, acc2[t], 0, 0, 0);
    }
  }

  #pragma unroll
  for (int r = 0; r < 4; ++r){
    float s = acc2[0][r] + acc2[1][r];
    #pragma unroll
    for (int m = 1; m < 16; m <<= 1) s += __shfl_xor(s, m, 16);
    if (c == 0) pm2[h][quad * 4 + r] = s;
  }
  __syncthreads();
  float mean2[4], rstd2[4];
  #pragma unroll
  for (int r = 0; r < 4; ++r){
    int row = quad * 4 + r;
    mean2[r] = (pm2[0][row] + pm2[1][row] + pm2[2][row] + pm2[3][row]) * 0.0078125f;
  }
  #pragma unroll
  for (int r = 0; r < 4; ++r){
    float d0 = acc2[0][r] - mean2[r], d1 = acc2[1][r] - mean2[r];
    float s = d0 * d0 + d1 * d1;
    #pragma unroll
    for (int m = 1; m < 16; m <<= 1) s += __shfl_xor(s, m, 16);
    if (c == 0) pv2[h][quad * 4 + r] = s;
  }
  __syncthreads();
  #pragma unroll
  for (int r = 0; r < 4; ++r){
    int row = quad * 4 + r;
    rstd2[r] = rsqrtf((pv2[0][row] + pv2[1][row] + pv2[2][row] + pv2[3][row]) * 0.0078125f + 1e-5f);
  }
  #pragma unroll
  for (int t = 0; t < 2; ++t){
    int col = h * 32 + t * 16 + c;
    float gv = g2[col], bv = b2[col];
    #pragma unroll
    for (int r = 0; r < 4; ++r){
      float v = fmaxf((acc2[t][r] - mean2[r]) * rstd2[r] * gv + bv, 0.f);
      hlds[(quad * 4 + r) * 136 + col] = f2b(v);
    }
  }
  __syncthreads();

  {
    int row16 = tid >> 4, pos = (tid & 15) * 4;
    const uint* src = (const uint*)hlds + row16 * 68 + pos;
    uint* dst = fBw + (size_t)(rowg + row16) * 64 + pos;
    *(uint4*)dst = *(const uint4*)src;
  }
}

// ---------------- K3: masked KNN + pool ----------------
__device__ __forceinline__ u64 shfl64(u64 v, int src){
  int lo = __shfl((int)(uint)v, src, 64);
  int hi = __shfl((int)(uint)(v >> 32), src, 64);
  return ((u64)(uint)hi << 32) | (uint)lo;
}

__device__ __forceinline__ u64 bsort64(u64 key, int lane){
  #pragma unroll
  for (int k = 2; k <= 64; k <<= 1){
    #pragma unroll
    for (int j = k >> 1; j > 0; j >>= 1){
      u64 o = shfl64(key, lane ^ j);
      bool lower = (lane & j) == 0;
      bool down  = (lane & k) == 0;
      bool takeMin = (lower == down);
      bool oLess = o < key;
      key = (oLess == takeMin) ? o : key;
    }
  }
  return key;
}
__device__ __forceinline__ u64 bmerge64(u64 key, int lane){
  #pragma unroll
  for (int j = 32; j > 0; j >>= 1){
    u64 o = shfl64(key, lane ^ j);
    bool lower = (lane & j) == 0;
    bool oLess = o < key;
    key = (oLess == lower) ? o : key;
  }
  return key;
}

__device__ __attribute__((noinline)) u64 drainx(u64* ldsq, int qcount, int lane){
  u64 a = (lane < qcount) ? ldsq[lane] : ~0ull;
  a = bsort64(a, lane);
  if (qcount > 64){
    u64 b = (64 + lane < qcount) ? ldsq[64 + lane] : ~0ull;
    b = bsort64(b, lane);
    u64 br = shfl64(b, 63 - lane);
    a = a < br ? a : br;
    a = bmerge64(a, lane);
  }
  if (lane < 16) ldsq[lane] = a;
  return a;
}

// proven updq (R7/R8): coarse 16-step ballot bound + compact + guard
__device__ __forceinline__ void updq(u64* ql, int& qc, int& nx, float& thr,
                                     float qw, int lane){
  int q = qc;
  u64 k0 = (lane < q) ? ql[lane] : ~0ull;
  u64 k1 = (64 + lane < q) ? ql[64 + lane] : ~0ull;
  uint h0 = (uint)(k0 >> 32), h1 = (uint)(k1 >> 32);
  uint m = h0 < h1 ? h0 : h1;
  uint v = 0u;
  #pragma unroll
  for (int b = 31; b >= 16; --b){
    uint tv = v | (1u << b);
    if (__popcll(__ballot(m < tv)) < 16) v = tv;
  }
  uint vb = (v >= 0xFFFF0000u) ? 0xFFFFFFFFu : (v + 0x10000u);

  bool kp0 = (h0 <= vb);
  u64 bal0 = __ballot(kp0);
  int r0 = __builtin_amdgcn_mbcnt_lo((uint)bal0, 0);
  r0 = __builtin_amdgcn_mbcnt_hi((uint)(bal0 >> 32), r0);
  if (kp0) ql[r0] = k0;
  int c0 = __popcll(bal0);
  bool kp1 = (h1 <= vb);
  u64 bal1 = __ballot(kp1);
  int r1 = __builtin_amdgcn_mbcnt_lo((uint)bal1, 0);
  r1 = __builtin_amdgcn_mbcnt_hi((uint)(bal1 >> 32), r1);
  if (kp1) ql[c0 + r1] = k1;
  int out = c0 + __popcll(bal1);

  uint hb = vb;
  if (out > 31){
    u64 a = drainx(ql, out, lane);
    hb = (uint)(shfl64(a, 15) >> 32);
    out = 16;
  }
  qc = out;
  nx = out + 33;
  thr = unford(hb) + 1e-3f - qw;
}

__device__ __forceinline__ int nextbit(u64& m0, u64& m1){
  if (m0){ int b = __builtin_ctzll(m0); m0 &= m0 - 1; return b; }
  if (m1){ int b = __builtin_ctzll(m1); m1 &= m1 - 1; return b + 64; }
  return -1;
}

// Block = 4 waves x 2 sequential queries. Own chunk first -> one updq -> valid
// d2thr0; 128-bit visit mask = 2 ballots on precomputed AABB lower bounds
// (superset of needed chunks since d2thr only tightens); bit-walk with 1-deep
// point prefetch. Keys (ford(exact d2), origIdx) are visit-order independent.
__global__ __launch_bounds__(256) void knn_pool_k(const float4* __restrict__ sCF,
                                                  const uint* __restrict__ oIdx,
                                                  const uint* __restrict__ sPos,
                                                  const float4* __restrict__ cBB,
                                                  const int* __restrict__ keep,
                                                  const uint* __restrict__ fB32,
                                                  float* __restrict__ out1){
  __shared__ u64 q8[4][2][128];
  int tid = threadIdx.x, lane = tid & 63;
  int wv = tid >> 6;
  int g0 = blockIdx.x * 8 + wv * 2;
  int n = g0 >> 11;
  int i0 = g0 & 2047;
  const float4* base = sCF + (n << 13);
  const uint* oix = oIdx + (n << 13);
  const float4* bb = cBB + (n << 8);

  u64 res[2];
  #pragma unroll
  for (int qi = 0; qi < 2; ++qi){
    int iq = i0 + qi;
    uint pos = sPos[(n << 13) + keep[iq]];
    float4 qv = base[pos];
    int cs = (int)(pos >> 6);
    float qw = qv.w;
    float q2x = -2.f * qv.x, q2y = -2.f * qv.y, q2z = -2.f * qv.z;

    // per-lane AABB lower bounds for chunks lane and lane+64
    float lb0, lb1;
    {
      float4 mn = bb[lane * 2], mx = bb[lane * 2 + 1];
      float dx = fmaxf(fmaxf(mn.x - qv.x, qv.x - mx.x), 0.f);
      float dy = fmaxf(fmaxf(mn.y - qv.y, qv.y - mx.y), 0.f);
      float dz = fmaxf(fmaxf(mn.z - qv.z, qv.z - mx.z), 0.f);
      lb0 = __builtin_fmaf(dx, dx, __builtin_fmaf(dy, dy, dz * dz));
      mn = bb[(lane + 64) * 2]; mx = bb[(lane + 64) * 2 + 1];
      dx = fmaxf(fmaxf(mn.x - qv.x, qv.x - mx.x), 0.f);
      dy = fmaxf(fmaxf(mn.y - qv.y, qv.y - mx.y), 0.f);
      dz = fmaxf(fmaxf(mn.z - qv.z, qv.z - mx.z), 0.f);
      lb1 = __builtin_fmaf(dx, dx, __builtin_fmaf(dy, dy, dz * dz));
    }

    float thr = 3.4e38f;
    int qc = 0, nx = 49;
    u64* ql = q8[wv][qi];

    #define PROCC(cf, c) { \
      float s = __builtin_fmaf(q2x, (cf).x, __builtin_fmaf(q2y, (cf).y, \
                __builtin_fmaf(q2z, (cf).z, (cf).w))); \
      u64 bal = __ballot(s <= thr); \
      if (bal){ \
        if (s <= thr){ \
          float d2; \
          { \
            _Pragma("clang fp contract(off)") \
            float dot = qv.x*(cf).x + qv.y*(cf).y + qv.z*(cf).z; \
            d2 = (qw + (cf).w) - 2.0f * dot; \
          } \
          uint oj = oix[((c) << 6) + lane]; \
          int rel = __builtin_amdgcn_mbcnt_lo((uint)bal, 0); \
          rel = __builtin_amdgcn_mbcnt_hi((uint)(bal >> 32), rel); \
          ql[qc + rel] = ((u64)ford(d2) << 32) | oj; \
        } \
        qc += __popcll(bal); \
        if (qc >= nx) updq(ql, qc, nx, thr, qw, lane); \
      } \
    }

    // own chunk: 64 pts, thr=inf -> full ballot -> qc=64 >= 49 -> one updq
    {
      float4 cf = base[(cs << 6) + lane];
      PROCC(cf, cs);
    }
    float d2thr = thr + qw;                    // valid upper bound on 16th d2

    // visit mask (superset of needed); clear own chunk
    u64 m0 = __ballot(lb0 <= d2thr);
    u64 m1 = __ballot(lb1 <= d2thr);
    if (cs < 64) m0 &= ~(1ull << cs);
    else         m1 &= ~(1ull << (cs - 64));

    // bit-walk with 1-deep prefetch
    int c = nextbit(m0, m1);
    float4 cf;
    if (c >= 0) cf = base[(c << 6) + lane];
    while (c >= 0){
      int c2 = nextbit(m0, m1);
      float4 cf2;
      if (c2 >= 0) cf2 = base[(c2 << 6) + lane];
      PROCC(cf, c);
      c = c2; cf = cf2;
    }
    #undef PROCC

    res[qi] = drainx(ql, qc, lane);
  }

  // pooling (fmod quirk via &2047 on original indices)
  const uint* frow = fB32 + ((size_t)(n << 11) << 6);
  float a0 = -3.4e38f, a1v = -3.4e38f, b0 = -3.4e38f, b1v = -3.4e38f;
  #pragma unroll
  for (int k = 0; k < 16; ++k){
    int idxA = (int)(shfl64(res[0], k) & 2047u);
    int idxB = (int)(shfl64(res[1], k) & 2047u);
    uint uA = frow[((size_t)idxA << 6) + lane];
    uint uB = frow[((size_t)idxB << 6) + lane];
    a0  = fmaxf(a0,  __uint_as_float((uA & 0xFFFFu) << 16));
    a1v = fmaxf(a1v, __uint_as_float((uA >> 16) << 16));
    b0  = fmaxf(b0,  __uint_as_float((uB & 0xFFFFu) << 16));
    b1v = fmaxf(b1v, __uint_as_float((uB >> 16) << 16));
  }
  float2* oA = (float2*)(out1 + (size_t)(i0 * 8 + n) * 128);
  float2* oB = (float2*)(out1 + (size_t)((i0 + 1) * 8 + n) * 128);
  oA[lane] = make_float2(a0, a1v);
  oB[lane] = make_float2(b0, b1v);
}

extern "C" void kernel_launch(void* const* d_in, const int* in_sizes, int n_in,
                              void* d_out, int out_size, void* d_ws, size_t ws_size,
                              hipStream_t stream){
  const float* coords = (const float*)d_in[0];
  const float* feat   = (const float*)d_in[1];
  const float* w1     = (const float*)d_in[2];
  const float* g1     = (const float*)d_in[3];
  const float* b1     = (const float*)d_in[4];
  const float* w2     = (const float*)d_in[5];
  const float* g2     = (const float*)d_in[6];
  const float* b2     = (const float*)d_in[7];
  const int*   keep   = (const int*)d_in[8];
  float* out0 = (float*)d_out;                    // keep_coords [2048,8,3]
  float* out1 = out0 + 49152;                     // pool_features [2048,8,128]

  char* ws = (char*)d_ws;
  // layout (cF/cellId dead after sort_k; fB overwrites them in mlp_k):
  float4* cF     = (float4*)ws;                           // 1 MB   @ 0
  uint*   cellId = (uint*)(ws + (1 << 20));               // 256 KB @ 1M
  uint*   fB     = (uint*)ws;                             // 4 MB   @ 0 (after sort)
  float4* sCF    = (float4*)(ws + (4 << 20));             // 1 MB   @ 4M
  uint*   oIdx   = (uint*)(ws + (5 << 20));               // 256 KB @ 5M
  uint*   sPos   = oIdx + 65536;                          // 256 KB
  float4* cBB    = (float4*)(ws + (5 << 20) + (512 << 10)); // 32 KB
  ushort* pw1    = (ushort*)(ws + (6 << 20));             // 16 KB @ 6M
  ushort* pw2    = pw1 + 8192;                            // 32 KB

  hipLaunchKernelGGL(prep_pack_k, dim3(544), dim3(256), 0, stream,
                     coords, keep, w1, w2, cF, cellId, out0, pw1, pw2);
  hipLaunchKernelGGL(sort_k, dim3(8), dim3(256), 0, stream,
                     cF, cellId, sCF, oIdx, sPos, cBB);
  hipLaunchKernelGGL(mlp_k, dim3(1024), dim3(256), 0, stream,
                     feat, pw1, g1, b1, pw2, g2, b2, fB);
  hipLaunchKernelGGL(knn_pool_k, dim3(2048), dim3(256), 0, stream,
                     sCF, oIdx, sPos, cBB, keep, fB, out1);
}

// Round 10
// 182.392 us; speedup vs baseline: 1.2642x; 1.2642x over previous
//
#include <hip/hip_runtime.h>
#include <stdint.h>

// Problem constants
#define L_    8192
#define N_    8
#define L2_   2048
#define K_    16

typedef unsigned int uint;
typedef unsigned short ushort;
typedef unsigned long long u64;
typedef __attribute__((ext_vector_type(8))) short bh8;   // 8 bf16 (4 VGPRs)
typedef __attribute__((ext_vector_type(4))) float f32x4; // MFMA C/D

// round-to-nearest-even f32 -> bf16 (monotone)
__device__ __forceinline__ ushort f2b(float f){
  uint u = __float_as_uint(f);
  return (ushort)((u + 0x7FFFu + ((u >> 16) & 1u)) >> 16);
}
// monotone float->uint mapping
__device__ __forceinline__ uint ford(float f){
  uint u = __float_as_uint(f);
  return u ^ ((uint)((int)u >> 31) | 0x80000000u);
}
__device__ __forceinline__ float unford(uint u){
  uint v = (u & 0x80000000u) ? (u ^ 0x80000000u) : ~u;
  return __uint_as_float(v);
}

__device__ __forceinline__ void ld8(float* t, const float* p){
  float4 a = *(const float4*)p; float4 b = *(const float4*)(p + 4);
  t[0]=a.x; t[1]=a.y; t[2]=a.z; t[3]=a.w; t[4]=b.x; t[5]=b.y; t[6]=b.z; t[7]=b.w;
}
__device__ __forceinline__ bh8 pack8(const float* v){
  bh8 r;
  #pragma unroll
  for (int j = 0; j < 8; ++j) r[j] = (short)f2b(v[j]);
  return r;
}

// 4-bit spread for Morton interleave
__device__ __forceinline__ uint sp4(uint v){
  return (v & 1u) | ((v & 2u) << 2) | ((v & 4u) << 4) | ((v & 8u) << 6);
}
__device__ __forceinline__ int cell16(float x){
  int i = (int)floorf((x + 4.f) * 2.f);
  return i < 0 ? 0 : (i > 15 ? 15 : i);
}

// ---------------- K0: prep = weight pack + cF+cellId + keep_coords (R9-identical) ----------------
__global__ __launch_bounds__(256) void prep_pack_k(const float* __restrict__ coords,
                                                   const int* __restrict__ keep,
                                                   const float* __restrict__ w1,
                                                   const float* __restrict__ w2,
                                                   float4* __restrict__ cF,
                                                   uint* __restrict__ cellId,
                                                   float* __restrict__ out0,
                                                   ushort* __restrict__ pw1,
                                                   ushort* __restrict__ pw2){
  int blk = blockIdx.x;
  int tid = threadIdx.x;
  if (blk < 96){
    int e = blk * 256 + tid;                   // e < 24576
    if (e < 8192) pw1[e] = f2b(w1[e]);
    else          pw2[e - 8192] = f2b(w2[e - 8192]);
  } else if (blk < 352){
    int e = (blk - 96) * 256 + tid;            // e = l*8+n, e < 65536
    int l = e >> 3, n = e & 7;
    const float* cr = coords + (size_t)e * 3;
    float x = cr[0], y = cr[1], z = cr[2];
    float cc;
    {
      #pragma clang fp contract(off)
      cc = x*x + y*y + z*z;                    // identical to reference sum(c*c,-1)
    }
    cF[(n << 13) + l] = make_float4(x, y, z, cc);
    uint mort = (sp4((uint)cell16(x)) << 2) | (sp4((uint)cell16(y)) << 1)
              | sp4((uint)cell16(z));          // 12-bit Morton: compact chunks
    cellId[(n << 13) + l] = mort;
  } else {
    int t = (blk - 352) * 256 + tid;           // t < 49152
    int i = t / 24; int rem = t - i * 24;
    out0[t] = coords[(size_t)keep[i] * 24 + rem];
  }
}

// ---------------- K1: per-n counting sort by Morton cell; AABB fused into scatter ----------------
__global__ __launch_bounds__(256) void sort_k(const float4* __restrict__ cF,
                                              const uint* __restrict__ cellId,
                                              float4* __restrict__ sCF,
                                              uint* __restrict__ oIdx,
                                              uint* __restrict__ sPos,
                                              float4* __restrict__ cBB){
  __shared__ uint hist[4096];                  // 16 KB; becomes offsets in-place
  __shared__ uint wsum[4];
  __shared__ uint bmn[128][3], bmx[128][3];    // 3 KB chunk AABBs (ford-encoded)
  int n = blockIdx.x;
  int tid = threadIdx.x, lane = tid & 63, wv = tid >> 6;
  const uint* cid = cellId + (n << 13);
  const float4* cf = cF + (n << 13);

  for (int i = tid; i < 4096; i += 256) hist[i] = 0;
  if (tid < 128){
    bmn[tid][0] = bmn[tid][1] = bmn[tid][2] = 0xFFFFFFFFu;
    bmx[tid][0] = bmx[tid][1] = bmx[tid][2] = 0u;
  }
  __syncthreads();
  for (int t = tid; t < 8192; t += 256)
    atomicAdd(&hist[cid[t]], 1u);              // coalesced read + LDS atomic
  __syncthreads();
  // exclusive scan in place: thread owns cells [16t, 16t+16)
  uint tt = 0;
  #pragma unroll
  for (int j = 0; j < 16; ++j) tt += hist[tid * 16 + j];
  uint sc = tt;
  #pragma unroll
  for (int m = 1; m < 64; m <<= 1){
    uint o = __shfl_up(sc, m, 64);
    if (lane >= m) sc += o;
  }
  if (lane == 63) wsum[wv] = sc;
  __syncthreads();
  uint wbase = 0;
  for (int w = 0; w < wv; ++w) wbase += wsum[w];
  uint run = wbase + sc - tt;
  #pragma unroll
  for (int j = 0; j < 16; ++j){
    uint v = hist[tid * 16 + j];
    hist[tid * 16 + j] = run;
    run += v;
  }
  __syncthreads();
  // scatter + fused AABB accumulation (ford encoding is monotone -> LDS
  // atomicMin/Max in ford space == float min/max). Intra-cell order is
  // nondeterministic: harmless, selection keys are exact (d2, origIdx).
  for (int t = tid; t < 8192; t += 256){
    float4 p = cf[t];
    uint pos = atomicAdd(&hist[cid[t]], 1u);
    sCF[(n << 13) + pos] = p;
    oIdx[(n << 13) + pos] = (uint)t;
    sPos[(n << 13) + t]   = pos;
    int ch = (int)(pos >> 6);
    atomicMin(&bmn[ch][0], ford(p.x)); atomicMax(&bmx[ch][0], ford(p.x));
    atomicMin(&bmn[ch][1], ford(p.y)); atomicMax(&bmx[ch][1], ford(p.y));
    atomicMin(&bmn[ch][2], ford(p.z)); atomicMax(&bmx[ch][2], ford(p.z));
  }
  __syncthreads();
  if (tid < 128){
    cBB[(n << 8) + tid * 2] = make_float4(unford(bmn[tid][0]), unford(bmn[tid][1]),
                                          unford(bmn[tid][2]), 0.f);
    cBB[(n << 8) + tid * 2 + 1] = make_float4(unford(bmx[tid][0]), unford(bmx[tid][1]),
                                              unford(bmx[tid][2]), 0.f);
  }
}

// ---------------- K2: MFMA MLP, dim-split 4 ways (R5-identical) ----------------
__global__ __launch_bounds__(256) void mlp_k(const float* __restrict__ feat,
                                             const ushort* __restrict__ pw1,
                                             const float* __restrict__ g1,
                                             const float* __restrict__ b1,
                                             const ushort* __restrict__ pw2,
                                             const float* __restrict__ g2,
                                             const float* __restrict__ b2,
                                             uint* __restrict__ fBw){
  __shared__ ushort hlds[16 * 136];
  __shared__ float pm1[4][16], pv1[4][16], pm2[4][16], pv2[4][16];
  int tid = threadIdx.x;
  int lane = tid & 63;
  int h = __builtin_amdgcn_readfirstlane(tid >> 6);
  int quad = lane >> 4, c = lane & 15;
  int rowg = blockIdx.x * 16;

  bh8 a1[2];
  {
    int rg = rowg + c; int l = rg & 2047, nb = rg >> 11;
    const float* xr = feat + (size_t)((l << 3) + nb) * 64 + quad * 8;
    float t0[8];
    ld8(t0, xr);      a1[0] = pack8(t0);
    ld8(t0, xr + 32); a1[1] = pack8(t0);
  }

  f32x4 acc1[2];
  acc1[0] = (f32x4){0.f,0.f,0.f,0.f}; acc1[1] = (f32x4){0.f,0.f,0.f,0.f};
  #pragma unroll
  for (int s = 0; s < 2; ++s){
    #pragma unroll
    for (int t = 0; t < 2; ++t){
      bh8 wb = *(const bh8*)(pw1 + (size_t)(h * 32 + t * 16 + c) * 64 + s * 32 + quad * 8);
      acc1[t] = __builtin_amdgcn_mfma_f32_16x16x32_bf16(a1[s], wb, acc1[t], 0, 0, 0);
    }
  }

  #pragma unroll
  for (int r = 0; r < 4; ++r){
    float s = acc1[0][r] + acc1[1][r];
    #pragma unroll
    for (int m = 1; m < 16; m <<= 1) s += __shfl_xor(s, m, 16);
    if (c == 0) pm1[h][quad * 4 + r] = s;
  }
  __syncthreads();
  float mean1[4], rstd1[4];
  #pragma unroll
  for (int r = 0; r < 4; ++r){
    int row = quad * 4 + r;
    mean1[r] = (pm1[0][row] + pm1[1][row] + pm1[2][row] + pm1[3][row]) * 0.0078125f;
  }
  #pragma unroll
  for (int r = 0; r < 4; ++r){
    float d0 = acc1[0][r] - mean1[r], d1 = acc1[1][r] - mean1[r];
    float s = d0 * d0 + d1 * d1;
    #pragma unroll
    for (int m = 1; m < 16; m <<= 1) s += __shfl_xor(s, m, 16);
    if (c == 0) pv1[h][quad * 4 + r] = s;
  }
  __syncthreads();
  #pragma unroll
  for (int r = 0; r < 4; ++r){
    int row = quad * 4 + r;
    rstd1[r] = rsqrtf((pv1[0][row] + pv1[1][row] + pv1[2][row] + pv1[3][row]) * 0.0078125f + 1e-5f);
  }
  #pragma unroll
  for (int t = 0; t < 2; ++t){
    int col = h * 32 + t * 16 + c;
    float gv = g1[col], bv = b1[col];
    #pragma unroll
    for (int r = 0; r < 4; ++r){
      float v = (acc1[t][r] - mean1[r]) * rstd1[r] * gv + bv;
      hlds[(quad * 4 + r) * 136 + col] = f2b(v);
    }
  }
  __syncthreads();

  f32x4 acc2[2];
  acc2[0] = (f32x4){0.f,0.f,0.f,0.f}; acc2[1] = (f32x4){0.f,0.f,0.f,0.f};
  #pragma unroll
  for (int s = 0; s < 4; ++s){
    bh8 af = *(const bh8*)(hlds + c * 136 + s * 32 + quad * 8);
    #pragma unroll
    for (int t = 0; t < 2; ++t){
      bh8 wb = *(const bh8*)(pw2 + (size_t)(h * 32 + t * 16 + c) * 128 + s * 32 + quad * 8);
      acc2[t] = __builtin_amdgcn_mfma_f32_16x16x32_bf16(af, wb, acc2[t], 0, 0, 0);
    }
  }

  #pragma unroll
  for (int r = 0; r < 4; ++r){
    float s = acc2[0][r] + acc2[1][r];
    #pragma unroll
    for (int m = 1; m < 16; m <<= 1) s += __shfl_xor(s, m, 16);
    if (c == 0) pm2[h][quad * 4 + r] = s;
  }
  __syncthreads();
  float mean2[4], rstd2[4];
  #pragma unroll
  for (int r = 0; r < 4; ++r){
    int row = quad * 4 + r;
    mean2[r] = (pm2[0][row] + pm2[1][row] + pm2[2][row] + pm2[3][row]) * 0.0078125f;
  }
  #pragma unroll
  for (int r = 0; r < 4; ++r){
    float d0 = acc2[0][r] - mean2[r], d1 = acc2[1][r] - mean2[r];
    float s = d0 * d0 + d1 * d1;
    #pragma unroll
    for (int m = 1; m < 16; m <<= 1) s += __shfl_xor(s, m, 16);
    if (c == 0) pv2[h][quad * 4 + r] = s;
  }
  __syncthreads();
  #pragma unroll
  for (int r = 0; r < 4; ++r){
    int row = quad * 4 + r;
    rstd2[r] = rsqrtf((pv2[0][row] + pv2[1][row] + pv2[2][row] + pv2[3][row]) * 0.0078125f + 1e-5f);
  }
  #pragma unroll
  for (int t = 0; t < 2; ++t){
    int col = h * 32 + t * 16 + c;
    float gv = g2[col], bv = b2[col];
    #pragma unroll
    for (int r = 0; r < 4; ++r){
      float v = fmaxf((acc2[t][r] - mean2[r]) * rstd2[r] * gv + bv, 0.f);
      hlds[(quad * 4 + r) * 136 + col] = f2b(v);
    }
  }
  __syncthreads();

  {
    int row16 = tid >> 4, pos = (tid & 15) * 4;
    const uint* src = (const uint*)hlds + row16 * 68 + pos;
    uint* dst = fBw + (size_t)(rowg + row16) * 64 + pos;
    *(uint4*)dst = *(const uint4*)src;
  }
}

// ---------------- K3: pruned KNN + pool (R8's proven sequential-walk loop) ----------------
__device__ __forceinline__ u64 shfl64(u64 v, int src){
  int lo = __shfl((int)(uint)v, src, 64);
  int hi = __shfl((int)(uint)(v >> 32), src, 64);
  return ((u64)(uint)hi << 32) | (uint)lo;
}

__device__ __forceinline__ u64 bsort64(u64 key, int lane){
  #pragma unroll
  for (int k = 2; k <= 64; k <<= 1){
    #pragma unroll
    for (int j = k >> 1; j > 0; j >>= 1){
      u64 o = shfl64(key, lane ^ j);
      bool lower = (lane & j) == 0;
      bool down  = (lane & k) == 0;
      bool takeMin = (lower == down);
      bool oLess = o < key;
      key = (oLess == takeMin) ? o : key;
    }
  }
  return key;
}
__device__ __forceinline__ u64 bmerge64(u64 key, int lane){
  #pragma unroll
  for (int j = 32; j > 0; j >>= 1){
    u64 o = shfl64(key, lane ^ j);
    bool lower = (lane & j) == 0;
    bool oLess = o < key;
    key = (oLess == lower) ? o : key;
  }
  return key;
}

__device__ __attribute__((noinline)) u64 drainx(u64* ldsq, int qcount, int lane){
  u64 a = (lane < qcount) ? ldsq[lane] : ~0ull;
  a = bsort64(a, lane);
  if (qcount > 64){
    u64 b = (64 + lane < qcount) ? ldsq[64 + lane] : ~0ull;
    b = bsort64(b, lane);
    u64 br = shfl64(b, 63 - lane);
    a = a < br ? a : br;
    a = bmerge64(a, lane);
  }
  if (lane < 16) ldsq[lane] = a;
  return a;
}

// proven updq: coarse 16-step ballot bound + compact + guard
__device__ __forceinline__ void updq(u64* ql, int& qc, int& nx, float& thr,
                                     float qw, int lane){
  int q = qc;
  u64 k0 = (lane < q) ? ql[lane] : ~0ull;
  u64 k1 = (64 + lane < q) ? ql[64 + lane] : ~0ull;
  uint h0 = (uint)(k0 >> 32), h1 = (uint)(k1 >> 32);
  uint m = h0 < h1 ? h0 : h1;
  uint v = 0u;
  #pragma unroll
  for (int b = 31; b >= 16; --b){
    uint tv = v | (1u << b);
    if (__popcll(__ballot(m < tv)) < 16) v = tv;
  }
  uint vb = (v >= 0xFFFF0000u) ? 0xFFFFFFFFu : (v + 0x10000u);

  bool kp0 = (h0 <= vb);
  u64 bal0 = __ballot(kp0);
  int r0 = __builtin_amdgcn_mbcnt_lo((uint)bal0, 0);
  r0 = __builtin_amdgcn_mbcnt_hi((uint)(bal0 >> 32), r0);
  if (kp0) ql[r0] = k0;
  int c0 = __popcll(bal0);
  bool kp1 = (h1 <= vb);
  u64 bal1 = __ballot(kp1);
  int r1 = __builtin_amdgcn_mbcnt_lo((uint)bal1, 0);
  r1 = __builtin_amdgcn_mbcnt_hi((uint)(bal1 >> 32), r1);
  if (kp1) ql[c0 + r1] = k1;
  int out = c0 + __popcll(bal1);

  uint hb = vb;
  if (out > 31){
    u64 a = drainx(ql, out, lane);
    hb = (uint)(shfl64(a, 15) >> 32);
    out = 16;
  }
  qc = out;
  nx = out + 33;
  thr = unford(hb) + 1e-3f - qw;
}

// Block = 4 waves x 2 sequential queries. Sequential walk over all 128 chunks
// starting at the query's own chunk; per-chunk uniform AABB lower-bound test
// (cheap shfl+cmp busy-work keeps duty high) skips the 64-pt screen when
// lb > d2thr. Morton chunks make AABBs tight in all axes -> high skip rate.
// Pruning validity: d2thr = thr+qw >= true 16th d2 + 1e-3 slack >> AABB fp err.
// Keys (ford(exact d2), origIdx) are visit-order independent.
__global__ __launch_bounds__(256) void knn_pool_k(const float4* __restrict__ sCF,
                                                  const uint* __restrict__ oIdx,
                                                  const uint* __restrict__ sPos,
                                                  const float4* __restrict__ cBB,
                                                  const int* __restrict__ keep,
                                                  const uint* __restrict__ fB32,
                                                  float* __restrict__ out1){
  __shared__ u64 q8[4][2][128];
  int tid = threadIdx.x, lane = tid & 63;
  int wv = tid >> 6;
  int g0 = blockIdx.x * 8 + wv * 2;
  int n = g0 >> 11;
  int i0 = g0 & 2047;
  const float4* base = sCF + (n << 13);
  const uint* oix = oIdx + (n << 13);
  const float4* bb = cBB + (n << 8);

  u64 res[2];
  #pragma unroll
  for (int qi = 0; qi < 2; ++qi){
    int iq = i0 + qi;
    uint pos = sPos[(n << 13) + keep[iq]];
    float4 qv = base[pos];
    int cs = (int)(pos >> 6);                  // query's own chunk
    float qw = qv.w;
    float q2x = -2.f * qv.x, q2y = -2.f * qv.y, q2z = -2.f * qv.z;

    // per-lane AABB lower bounds for chunks lane and lane+64
    float lb0, lb1;
    {
      float4 mn = bb[lane * 2], mx = bb[lane * 2 + 1];
      float dx = fmaxf(fmaxf(mn.x - qv.x, qv.x - mx.x), 0.f);
      float dy = fmaxf(fmaxf(mn.y - qv.y, qv.y - mx.y), 0.f);
      float dz = fmaxf(fmaxf(mn.z - qv.z, qv.z - mx.z), 0.f);
      lb0 = __builtin_fmaf(dx, dx, __builtin_fmaf(dy, dy, dz * dz));
      mn = bb[(lane + 64) * 2]; mx = bb[(lane + 64) * 2 + 1];
      dx = fmaxf(fmaxf(mn.x - qv.x, qv.x - mx.x), 0.f);
      dy = fmaxf(fmaxf(mn.y - qv.y, qv.y - mx.y), 0.f);
      dz = fmaxf(fmaxf(mn.z - qv.z, qv.z - mx.z), 0.f);
      lb1 = __builtin_fmaf(dx, dx, __builtin_fmaf(dy, dy, dz * dz));
    }

    float thr = 3.4e38f, d2thr = 3.4e38f;
    int qc = 0, nx = 49;
    u64* ql = q8[wv][qi];

    for (int ii = 0; ii < 128; ++ii){
      int c = (cs + ii) & 127;                 // wave-uniform; own chunk first
      float lbc = __shfl((c & 64) ? lb1 : lb0, c & 63, 64);
      if (lbc > d2thr) continue;               // uniform prune
      int j = (c << 6) + lane;
      float4 cf = base[j];
      float s = __builtin_fmaf(q2x, cf.x, __builtin_fmaf(q2y, cf.y,
                __builtin_fmaf(q2z, cf.z, cf.w)));
      u64 bal = __ballot(s <= thr);
      if (bal){
        if (s <= thr){
          float d2;
          {
            #pragma clang fp contract(off)
            float dot = qv.x*cf.x + qv.y*cf.y + qv.z*cf.z;
            d2 = (qw + cf.w) - 2.0f * dot;
          }
          uint oj = oix[j];
          int rel = __builtin_amdgcn_mbcnt_lo((uint)bal, 0);
          rel = __builtin_amdgcn_mbcnt_hi((uint)(bal >> 32), rel);
          ql[qc + rel] = ((u64)ford(d2) << 32) | oj;
        }
        qc += __popcll(bal);
        if (qc >= nx){
          updq(ql, qc, nx, thr, qw, lane);
          d2thr = thr + qw;
        }
      }
    }
    res[qi] = drainx(ql, qc, lane);
  }

  // pooling (fmod quirk via &2047 on original indices)
  const uint* frow = fB32 + ((size_t)(n << 11) << 6);
  float a0 = -3.4e38f, a1v = -3.4e38f, b0 = -3.4e38f, b1v = -3.4e38f;
  #pragma unroll
  for (int k = 0; k < 16; ++k){
    int idxA = (int)(shfl64(res[0], k) & 2047u);
    int idxB = (int)(shfl64(res[1], k) & 2047u);
    uint uA = frow[((size_t)idxA << 6) + lane];
    uint uB = frow[((size_t)idxB << 6) + lane];
    a0  = fmaxf(a0,  __uint_as_float((uA & 0xFFFFu) << 16));
    a1v = fmaxf(a1v, __uint_as_float((uA >> 16) << 16));
    b0  = fmaxf(b0,  __uint_as_float((uB & 0xFFFFu) << 16));
    b1v = fmaxf(b1v, __uint_as_float((uB >> 16) << 16));
  }
  float2* oA = (float2*)(out1 + (size_t)(i0 * 8 + n) * 128);
  float2* oB = (float2*)(out1 + (size_t)((i0 + 1) * 8 + n) * 128);
  oA[lane] = make_float2(a0, a1v);
  oB[lane] = make_float2(b0, b1v);
}

extern "C" void kernel_launch(void* const* d_in, const int* in_sizes, int n_in,
                              void* d_out, int out_size, void* d_ws, size_t ws_size,
                              hipStream_t stream){
  const float* coords = (const float*)d_in[0];
  const float* feat   = (const float*)d_in[1];
  const float* w1     = (const float*)d_in[2];
  const float* g1     = (const float*)d_in[3];
  const float* b1     = (const float*)d_in[4];
  const float* w2     = (const float*)d_in[5];
  const float* g2     = (const float*)d_in[6];
  const float* b2     = (const float*)d_in[7];
  const int*   keep   = (const int*)d_in[8];
  float* out0 = (float*)d_out;                    // keep_coords [2048,8,3]
  float* out1 = out0 + 49152;                     // pool_features [2048,8,128]

  char* ws = (char*)d_ws;
  // layout (cF/cellId dead after sort_k; fB overwrites them in mlp_k):
  float4* cF     = (float4*)ws;                           // 1 MB   @ 0
  uint*   cellId = (uint*)(ws + (1 << 20));               // 256 KB @ 1M
  uint*   fB     = (uint*)ws;                             // 4 MB   @ 0 (after sort)
  float4* sCF    = (float4*)(ws + (4 << 20));             // 1 MB   @ 4M
  uint*   oIdx   = (uint*)(ws + (5 << 20));               // 256 KB @ 5M
  uint*   sPos   = oIdx + 65536;                          // 256 KB
  float4* cBB    = (float4*)(ws + (5 << 20) + (512 << 10)); // 32 KB
  ushort* pw1    = (ushort*)(ws + (6 << 20));             // 16 KB @ 6M
  ushort* pw2    = pw1 + 8192;                            // 32 KB

  hipLaunchKernelGGL(prep_pack_k, dim3(544), dim3(256), 0, stream,
                     coords, keep, w1, w2, cF, cellId, out0, pw1, pw2);
  hipLaunchKernelGGL(sort_k, dim3(8), dim3(256), 0, stream,
                     cF, cellId, sCF, oIdx, sPos, cBB);
  hipLaunchKernelGGL(mlp_k, dim3(1024), dim3(256), 0, stream,
                     feat, pw1, g1, b1, pw2, g2, b2, fB);
  hipLaunchKernelGGL(knn_pool_k, dim3(2048), dim3(256), 0, stream,
                     sCF, oIdx, sPos, cBB, keep, fB, out1);
}